// Round 8
// baseline (378.851 us; speedup 1.0000x reference)
//
#include <hip/hip_runtime.h>
#include <hip/hip_bf16.h>
#include <stdint.h>

#define D 128
#define BSH 9                 // bucket = 512 nodes
#define BKN 512               // nodes per bucket
#define TILE 8192             // edges per bin_edges block

typedef __attribute__((ext_vector_type(8))) short short8;
typedef __attribute__((ext_vector_type(4))) float f32x4;

__device__ inline float bf16lo(uint32_t u){ return __uint_as_float(u << 16); }
__device__ inline float bf16hi(uint32_t u){ return __uint_as_float(u & 0xffff0000u); }
__device__ inline unsigned short f2bf(float f){
    union { __hip_bfloat16 h; unsigned short u; } cvt;
    cvt.h = __float2bfloat16(f);
    return cvt.u;
}

#define ACC8(q) \
    acc[0] += bf16lo(q.x); acc[1] += bf16hi(q.x); \
    acc[2] += bf16lo(q.y); acc[3] += bf16hi(q.y); \
    acc[4] += bf16lo(q.z); acc[5] += bf16hi(q.z); \
    acc[6] += bf16lo(q.w); acc[7] += bf16hi(q.w);

#define ACC4(q) \
    acc[0] += bf16lo(q.x); acc[1] += bf16hi(q.x); \
    acc[2] += bf16lo(q.y); acc[3] += bf16hi(q.y);

// ---------- binned CSR build (bucket = dst >> 9) ----------
__global__ void count_bkt(const int* __restrict__ dst, int* __restrict__ cnt, int E, int nbk){
    __shared__ int h[256];
    int t = threadIdx.x;
    for (int i = t; i < nbk; i += 256) h[i] = 0;
    __syncthreads();
    for (int e = blockIdx.x * 256 + t; e < E; e += gridDim.x * 256)
        atomicAdd(&h[dst[e] >> BSH], 1);
    __syncthreads();
    for (int i = t; i < nbk; i += 256) if (h[i]) atomicAdd(&cnt[i], h[i]);
}

__global__ void scan_bkt(const int* __restrict__ cnt, int* __restrict__ base,
                         int* __restrict__ bfill, int nb, int E){
    __shared__ int s[256];
    __shared__ int carry;
    int t = threadIdx.x;
    if (t == 0) carry = 0;
    __syncthreads();
    for (int start = 0; start < nb; start += 256){
        int i = start + t;
        int v = (i < nb) ? cnt[i] : 0;
        s[t] = v;
        __syncthreads();
        for (int o = 1; o < 256; o <<= 1){
            int x = (t >= o) ? s[t - o] : 0;
            __syncthreads();
            s[t] += x;
            __syncthreads();
        }
        int excl = carry + s[t] - v;
        if (i < nb){ base[i] = excl; bfill[i] = excl; }
        __syncthreads();
        if (t == 255) carry += s[255];
        __syncthreads();
    }
    if (t == 0) base[nb] = E;
}

// LDS-staged scatter: tile -> hist -> scan -> reserve -> LDS reorder -> dense run writes
__global__ __launch_bounds__(256) void bin_edges(
    const int* __restrict__ src, const int* __restrict__ dst,
    int* __restrict__ bfill, uint32_t* __restrict__ binbuf, int E, int nbk)
{
    __shared__ int hist[256];
    __shared__ int hbase[257];
    __shared__ int gbase[256];
    __shared__ int cur[256];
    __shared__ int sc[256];
    __shared__ uint32_t stg[TILE];
    int t = threadIdx.x;
    int tile0 = blockIdx.x * TILE;
    int cnt = min(TILE, E - tile0);

    for (int i = t; i < nbk; i += 256) hist[i] = 0;
    __syncthreads();
    for (int i = t; i < cnt; i += 256)
        atomicAdd(&hist[dst[tile0 + i] >> BSH], 1);
    __syncthreads();
    int v = (t < nbk) ? hist[t] : 0;
    sc[t] = v;
    __syncthreads();
    for (int o = 1; o < 256; o <<= 1){
        int x = (t >= o) ? sc[t - o] : 0;
        __syncthreads();
        sc[t] += x;
        __syncthreads();
    }
    if (t < nbk){
        int ex = sc[t] - v;
        hbase[t] = ex; cur[t] = ex;
        gbase[t] = v ? atomicAdd(&bfill[t], v) : 0;
    }
    if (t == 0) hbase[nbk] = cnt;
    __syncthreads();
    for (int i = t; i < cnt; i += 256){
        int d = dst[tile0 + i];
        int s_ = src[tile0 + i];
        int b = d >> BSH;
        int p = atomicAdd(&cur[b], 1);
        stg[p] = (uint32_t)s_ | ((uint32_t)(d & (BKN - 1)) << 17);
    }
    __syncthreads();
    for (int i = t; i < cnt; i += 256){
        int lo = 0, hi = nbk;
        while (hi - lo > 1){
            int mid = (lo + hi) >> 1;
            if (hbase[mid] <= i) lo = mid; else hi = mid;
        }
        binbuf[(size_t)gbase[lo] + (i - hbase[lo])] = stg[i];
    }
}

// one block per 512-node bucket: histogram -> scan -> roff + local csr scatter
__global__ __launch_bounds__(256) void fill_bucket(
    const uint32_t* __restrict__ binbuf, const int* __restrict__ bktbase,
    int* __restrict__ roff, int* __restrict__ csr, int n, int nbk)
{
    __shared__ int hist[BKN];
    __shared__ int hist2[BKN];
    __shared__ int hb2[BKN];
    __shared__ int sc[256];
    int b = blockIdx.x, t = threadIdx.x;
    int e0 = bktbase[b], e1 = bktbase[b + 1];
    int v0 = b << BSH;
    int nv = min(BKN, n - v0);

    hist[t] = 0; hist[t + 256] = 0;
    hist2[t] = 0; hist2[t + 256] = 0;
    __syncthreads();
    for (int e = e0 + t; e < e1; e += 256)
        atomicAdd(&hist[binbuf[e] >> 17], 1);
    __syncthreads();
    int a0 = hist[2 * t], a1 = hist[2 * t + 1];
    int own = a0 + a1;
    sc[t] = own;
    __syncthreads();
    for (int o = 1; o < 256; o <<= 1){
        int x = (t >= o) ? sc[t - o] : 0;
        __syncthreads();
        sc[t] += x;
        __syncthreads();
    }
    int ex = sc[t] - own;
    hb2[2 * t] = ex;
    hb2[2 * t + 1] = ex + a0;
    __syncthreads();
    for (int i = t; i < nv; i += 256) roff[v0 + i] = e0 + hb2[i];
    if (b == nbk - 1 && t == 0) roff[n] = e1;
    for (int e = e0 + t; e < e1; e += 256){
        uint32_t p = binbuf[e];
        int local = p >> 17;
        int pos = e0 + hb2[local] + atomicAdd(&hist2[local], 1);
        csr[pos] = (int)(p & 0x1FFFFu);
    }
}

// ---------- weight pre-transpose: WT[j][k] = bf16(Wcat[k][j]), Wcat = [Wl | Wr], NC=2*DOUT cols ----------
__global__ void wt_prep(const float* __restrict__ Wl, const float* __restrict__ Wr,
                        unsigned short* __restrict__ WT, int dout){
    int nc = dout * 2;
    int idx = blockIdx.x * 256 + threadIdx.x;
    if (idx >= nc * 128) return;
    int k = idx & 127, j = idx >> 7;
    float w = (j < dout) ? Wl[k * dout + j] : Wr[k * dout + (j - dout)];
    WT[j * 128 + k] = f2bf(w);
}

// ---------- dense GEMM: ylz = X @ [Wl|Wr] + [0|b]  (M=n, N=NC, K=128) ----------
// grid = (M/64, NC/128). A-tile (64x128 bf16 = 16KB) staged in LDS with XOR swizzle
// (byte ^= (row&7)<<4) so fragment ds_read_b128 is 2-way (free) instead of 16-way.
// Swapped-operand MFMA: mfma(W-frag, X-frag) -> lane holds 4 consecutive out-cols -> uint2 store.
template<int NC, bool AF32>
__global__ __launch_bounds__(256, 2) void dense_gemm(
    const unsigned short* __restrict__ xb, const float* __restrict__ xf,
    const unsigned short* __restrict__ WT, const float* __restrict__ bias,
    unsigned short* __restrict__ ylz, int n)
{
    constexpr int DOUT = NC / 2;
    __shared__ __align__(16) char As[64 * 256];
    int tid = threadIdx.x, lane = tid & 63, wave = tid >> 6;
    int rbase = blockIdx.x * 64;
    int lrow = lane & 15, lk = (lane >> 4) * 8;
    int colbase = blockIdx.y * 128 + wave * 32;

    // W fragments from global (L2-hot; issued early, overlap with staging)
    short8 bfr[4][2];
    #pragma unroll
    for (int kk = 0; kk < 4; kk++)
        #pragma unroll
        for (int cf = 0; cf < 2; cf++)
            bfr[kk][cf] = *reinterpret_cast<const short8*>(
                WT + (size_t)(colbase + cf * 16 + lrow) * 128 + kk * 32 + lk);

    // ---- stage A tile into LDS, coalesced + swizzled ----
    {
        int cb = (tid & 15) * 16;             // byte col within 256B row
        #pragma unroll
        for (int i = 0; i < 4; i++){
            int row = i * 16 + (tid >> 4);
            int grow = min(rbase + row, n - 1);
            uint4 q;
            if (AF32){
                const float* p = xf + (size_t)grow * 128 + (cb >> 1);
                float4 f0 = *reinterpret_cast<const float4*>(p);
                float4 f1 = *reinterpret_cast<const float4*>(p + 4);
                q.x = (uint32_t)f2bf(f0.x) | ((uint32_t)f2bf(f0.y) << 16);
                q.y = (uint32_t)f2bf(f0.z) | ((uint32_t)f2bf(f0.w) << 16);
                q.z = (uint32_t)f2bf(f1.x) | ((uint32_t)f2bf(f1.y) << 16);
                q.w = (uint32_t)f2bf(f1.z) | ((uint32_t)f2bf(f1.w) << 16);
            } else {
                q = *reinterpret_cast<const uint4*>(xb + (size_t)grow * 128 + (cb >> 1));
            }
            *reinterpret_cast<uint4*>(As + row * 256 + (cb ^ ((row & 7) << 4))) = q;
        }
    }
    __syncthreads();

    f32x4 acc[4][2];
    #pragma unroll
    for (int fr = 0; fr < 4; fr++)
        #pragma unroll
        for (int cf = 0; cf < 2; cf++)
            acc[fr][cf] = (f32x4){0.f, 0.f, 0.f, 0.f};

    #pragma unroll
    for (int kk = 0; kk < 4; kk++){
        short8 a[4];
        #pragma unroll
        for (int fr = 0; fr < 4; fr++){
            int row = fr * 16 + lrow;
            int cb = kk * 64 + (lane >> 4) * 16;
            a[fr] = *reinterpret_cast<const short8*>(As + row * 256 + (cb ^ ((row & 7) << 4)));
        }
        #pragma unroll
        for (int cf = 0; cf < 2; cf++)
            #pragma unroll
            for (int fr = 0; fr < 4; fr++)
                acc[fr][cf] = __builtin_amdgcn_mfma_f32_16x16x32_bf16(bfr[kk][cf], a[fr], acc[fr][cf], 0, 0, 0);
    }

    // bias per cf (col group), 4 consecutive cols per lane
    float4 bv[2];
    #pragma unroll
    for (int cf = 0; cf < 2; cf++){
        int cg = colbase + cf * 16 + (lane >> 4) * 4;
        bv[cf] = (cg >= DOUT) ? *reinterpret_cast<const float4*>(bias + (cg - DOUT))
                              : (float4){0.f, 0.f, 0.f, 0.f};
    }

    #pragma unroll
    for (int fr = 0; fr < 4; fr++){
        int row = rbase + fr * 16 + lrow;
        if (row < n){
            #pragma unroll
            for (int cf = 0; cf < 2; cf++){
                int cg = colbase + cf * 16 + (lane >> 4) * 4;
                uint2 o;
                o.x = (uint32_t)f2bf(acc[fr][cf][0] + bv[cf].x) |
                      ((uint32_t)f2bf(acc[fr][cf][1] + bv[cf].y) << 16);
                o.y = (uint32_t)f2bf(acc[fr][cf][2] + bv[cf].z) |
                      ((uint32_t)f2bf(acc[fr][cf][3] + bv[cf].w) << 16);
                *reinterpret_cast<uint2*>(ylz + (size_t)row * NC + cg) = o;
            }
        }
    }
}

// ---------- aggregation: h = relu(mean_gather(yl) + z), yl/z in ylz[N][256] ----------
__global__ __launch_bounds__(256, 8) void agg_relu(
    const unsigned short* __restrict__ ylz, const int* __restrict__ roff,
    const int* __restrict__ csr, unsigned short* __restrict__ hout, int n)
{
    int grp = threadIdx.x >> 4, li = threadIdx.x & 15;
    int v = blockIdx.x * 16 + grp;
    if (v >= n) return;
    int s0 = roff[v], s1 = roff[v + 1];
    const unsigned short* base = ylz + li * 8;
    float acc[8] = {0.f,0.f,0.f,0.f,0.f,0.f,0.f,0.f};
    int e = s0;
    for (; e + 8 <= s1; e += 8){
        int i0=csr[e],i1=csr[e+1],i2=csr[e+2],i3=csr[e+3];
        int i4=csr[e+4],i5=csr[e+5],i6=csr[e+6],i7=csr[e+7];
        uint4 q0 = *reinterpret_cast<const uint4*>(base + (size_t)i0 * 256);
        uint4 q1 = *reinterpret_cast<const uint4*>(base + (size_t)i1 * 256);
        uint4 q2 = *reinterpret_cast<const uint4*>(base + (size_t)i2 * 256);
        uint4 q3 = *reinterpret_cast<const uint4*>(base + (size_t)i3 * 256);
        uint4 q4 = *reinterpret_cast<const uint4*>(base + (size_t)i4 * 256);
        uint4 q5 = *reinterpret_cast<const uint4*>(base + (size_t)i5 * 256);
        uint4 q6 = *reinterpret_cast<const uint4*>(base + (size_t)i6 * 256);
        uint4 q7 = *reinterpret_cast<const uint4*>(base + (size_t)i7 * 256);
        ACC8(q0) ACC8(q1) ACC8(q2) ACC8(q3) ACC8(q4) ACC8(q5) ACC8(q6) ACC8(q7)
    }
    if (e < s1){
        int last = s1 - 1;
        int i0=csr[e];
        int i1=csr[min(e+1,last)],i2=csr[min(e+2,last)],i3=csr[min(e+3,last)];
        int i4=csr[min(e+4,last)],i5=csr[min(e+5,last)],i6=csr[min(e+6,last)],i7=csr[min(e+7,last)];
        uint4 z4 = make_uint4(0,0,0,0);
        uint4 q0 = *reinterpret_cast<const uint4*>(base + (size_t)i0 * 256);
        uint4 q1 = *reinterpret_cast<const uint4*>(base + (size_t)i1 * 256);
        uint4 q2 = *reinterpret_cast<const uint4*>(base + (size_t)i2 * 256);
        uint4 q3 = *reinterpret_cast<const uint4*>(base + (size_t)i3 * 256);
        uint4 q4 = *reinterpret_cast<const uint4*>(base + (size_t)i4 * 256);
        uint4 q5 = *reinterpret_cast<const uint4*>(base + (size_t)i5 * 256);
        uint4 q6 = *reinterpret_cast<const uint4*>(base + (size_t)i6 * 256);
        uint4 q7 = *reinterpret_cast<const uint4*>(base + (size_t)i7 * 256);
        if (e+1 > last) q1 = z4;
        if (e+2 > last) q2 = z4;
        if (e+3 > last) q3 = z4;
        if (e+4 > last) q4 = z4;
        if (e+5 > last) q5 = z4;
        if (e+6 > last) q6 = z4;
        if (e+7 > last) q7 = z4;
        ACC8(q0) ACC8(q1) ACC8(q2) ACC8(q3) ACC8(q4) ACC8(q5) ACC8(q6) ACC8(q7)
    }
    int d = s1 - s0;
    float inv = (d > 0) ? 1.0f / (float)d : 0.0f;
    uint4 zq = *reinterpret_cast<const uint4*>(ylz + (size_t)v * 256 + 128 + li * 8);
    float z0=bf16lo(zq.x), z1=bf16hi(zq.x), z2=bf16lo(zq.y), z3=bf16hi(zq.y);
    float z4_=bf16lo(zq.z), z5=bf16hi(zq.z), z6=bf16lo(zq.w), z7=bf16hi(zq.w);
    uint4 o;
    o.x = (uint32_t)f2bf(fmaxf(acc[0]*inv+z0,0.f)) | ((uint32_t)f2bf(fmaxf(acc[1]*inv+z1,0.f)) << 16);
    o.y = (uint32_t)f2bf(fmaxf(acc[2]*inv+z2,0.f)) | ((uint32_t)f2bf(fmaxf(acc[3]*inv+z3,0.f)) << 16);
    o.z = (uint32_t)f2bf(fmaxf(acc[4]*inv+z4_,0.f)) | ((uint32_t)f2bf(fmaxf(acc[5]*inv+z5,0.f)) << 16);
    o.w = (uint32_t)f2bf(fmaxf(acc[6]*inv+z6,0.f)) | ((uint32_t)f2bf(fmaxf(acc[7]*inv+z7,0.f)) << 16);
    *reinterpret_cast<uint4*>(hout + (size_t)v * 128 + li * 8) = o;
}

// ---------- final layer aggregation: out = mean_gather(yl2) + z2, fp32 out, ylz[N][128] ----------
__global__ __launch_bounds__(256, 8) void agg_out64(
    const unsigned short* __restrict__ ylz, const int* __restrict__ roff,
    const int* __restrict__ csr, float* __restrict__ out, int n)
{
    int grp = threadIdx.x >> 4, li = threadIdx.x & 15;
    int v = blockIdx.x * 16 + grp;
    if (v >= n) return;
    int s0 = roff[v], s1 = roff[v + 1];
    const unsigned short* base = ylz + li * 4;
    float acc[4] = {0.f,0.f,0.f,0.f};
    int e = s0;
    for (; e + 8 <= s1; e += 8){
        int i0=csr[e],i1=csr[e+1],i2=csr[e+2],i3=csr[e+3];
        int i4=csr[e+4],i5=csr[e+5],i6=csr[e+6],i7=csr[e+7];
        uint2 q0 = *reinterpret_cast<const uint2*>(base + (size_t)i0 * 128);
        uint2 q1 = *reinterpret_cast<const uint2*>(base + (size_t)i1 * 128);
        uint2 q2 = *reinterpret_cast<const uint2*>(base + (size_t)i2 * 128);
        uint2 q3 = *reinterpret_cast<const uint2*>(base + (size_t)i3 * 128);
        uint2 q4 = *reinterpret_cast<const uint2*>(base + (size_t)i4 * 128);
        uint2 q5 = *reinterpret_cast<const uint2*>(base + (size_t)i5 * 128);
        uint2 q6 = *reinterpret_cast<const uint2*>(base + (size_t)i6 * 128);
        uint2 q7 = *reinterpret_cast<const uint2*>(base + (size_t)i7 * 128);
        ACC4(q0) ACC4(q1) ACC4(q2) ACC4(q3) ACC4(q4) ACC4(q5) ACC4(q6) ACC4(q7)
    }
    if (e < s1){
        int last = s1 - 1;
        int i0=csr[e];
        int i1=csr[min(e+1,last)],i2=csr[min(e+2,last)],i3=csr[min(e+3,last)];
        int i4=csr[min(e+4,last)],i5=csr[min(e+5,last)],i6=csr[min(e+6,last)],i7=csr[min(e+7,last)];
        uint2 z2_ = make_uint2(0,0);
        uint2 q0 = *reinterpret_cast<const uint2*>(base + (size_t)i0 * 128);
        uint2 q1 = *reinterpret_cast<const uint2*>(base + (size_t)i1 * 128);
        uint2 q2 = *reinterpret_cast<const uint2*>(base + (size_t)i2 * 128);
        uint2 q3 = *reinterpret_cast<const uint2*>(base + (size_t)i3 * 128);
        uint2 q4 = *reinterpret_cast<const uint2*>(base + (size_t)i4 * 128);
        uint2 q5 = *reinterpret_cast<const uint2*>(base + (size_t)i5 * 128);
        uint2 q6 = *reinterpret_cast<const uint2*>(base + (size_t)i6 * 128);
        uint2 q7 = *reinterpret_cast<const uint2*>(base + (size_t)i7 * 128);
        if (e+1 > last) q1 = z2_;
        if (e+2 > last) q2 = z2_;
        if (e+3 > last) q3 = z2_;
        if (e+4 > last) q4 = z2_;
        if (e+5 > last) q5 = z2_;
        if (e+6 > last) q6 = z2_;
        if (e+7 > last) q7 = z2_;
        ACC4(q0) ACC4(q1) ACC4(q2) ACC4(q3) ACC4(q4) ACC4(q5) ACC4(q6) ACC4(q7)
    }
    int d = s1 - s0;
    float inv = (d > 0) ? 1.0f / (float)d : 0.0f;
    uint2 zq = *reinterpret_cast<const uint2*>(ylz + (size_t)v * 128 + 64 + li * 4);
    float4 o;
    o.x = acc[0]*inv + bf16lo(zq.x);
    o.y = acc[1]*inv + bf16hi(zq.x);
    o.z = acc[2]*inv + bf16lo(zq.y);
    o.w = acc[3]*inv + bf16hi(zq.y);
    *reinterpret_cast<float4*>(out + (size_t)v * 64 + li * 4) = o;
}

extern "C" void kernel_launch(void* const* d_in, const int* in_sizes, int n_in,
                              void* d_out, int out_size, void* d_ws, size_t ws_size,
                              hipStream_t stream)
{
    const float* x   = (const float*)d_in[0];
    const int*   ei  = (const int*)d_in[1];
    const float* Wl0 = (const float*)d_in[2];
    const float* Wr0 = (const float*)d_in[3];
    const float* b0  = (const float*)d_in[4];
    const float* Wl1 = (const float*)d_in[5];
    const float* Wr1 = (const float*)d_in[6];
    const float* b1  = (const float*)d_in[7];
    const float* Wl2 = (const float*)d_in[8];
    const float* Wr2 = (const float*)d_in[9];
    const float* b2  = (const float*)d_in[10];

    int N = in_sizes[0] / D;
    int E = in_sizes[1] / 2;
    const int* src = ei;
    const int* dst = ei + E;
    int NBK = (N + BKN - 1) >> BSH;

    char* ws = (char*)d_ws;
    size_t off = 0;
    auto alloc = [&](size_t bytes) -> void* {
        void* p = ws + off;
        off = (off + bytes + 255) & ~(size_t)255;
        return p;
    };
    int*      bktcnt  = (int*)alloc((size_t)NBK * 4);
    int*      bktbase = (int*)alloc(((size_t)NBK + 1) * 4);
    int*      bktfill = (int*)alloc((size_t)NBK * 4);
    int*      roff    = (int*)alloc(((size_t)N + 1) * 4);
    int*      csr     = (int*)alloc((size_t)E * 4);
    unsigned short* ylz = (unsigned short*)alloc((size_t)N * 256 * 2);   // also overlays binbuf
    unsigned short* h0  = (unsigned short*)alloc((size_t)N * D * 2);
    unsigned short* h1  = (unsigned short*)alloc((size_t)N * D * 2);
    unsigned short* WT0 = (unsigned short*)alloc((size_t)256 * 128 * 2);
    unsigned short* WT1 = (unsigned short*)alloc((size_t)256 * 128 * 2);
    unsigned short* WT2 = (unsigned short*)alloc((size_t)128 * 128 * 2);
    uint32_t* binbuf = (uint32_t*)ylz;   // binbuf dead before first ylz write

    hipMemsetAsync(bktcnt, 0, (size_t)NBK * 4, stream);

    count_bkt<<<512, 256, 0, stream>>>(dst, bktcnt, E, NBK);
    scan_bkt<<<1, 256, 0, stream>>>(bktcnt, bktbase, bktfill, NBK, E);
    bin_edges<<<(E + TILE - 1) / TILE, 256, 0, stream>>>(src, dst, bktfill, binbuf, E, NBK);
    fill_bucket<<<NBK, 256, 0, stream>>>(binbuf, bktbase, roff, csr, N, NBK);

    wt_prep<<<(256 * 128 + 255) / 256, 256, 0, stream>>>(Wl0, Wr0, WT0, 128);
    wt_prep<<<(256 * 128 + 255) / 256, 256, 0, stream>>>(Wl1, Wr1, WT1, 128);
    wt_prep<<<(128 * 128 + 255) / 256, 256, 0, stream>>>(Wl2, Wr2, WT2, 64);

    int gG = (N + 63) / 64;
    int gA = (N + 15) / 16;

    // layer 0: ylz = x @ [Wl0|Wr0] + [0|b0]  (fp32 A, converted during staging)
    dense_gemm<256, true ><<<dim3(gG, 2), 256, 0, stream>>>(nullptr, x, WT0, b0, ylz, N);
    agg_relu<<<gA, 256, 0, stream>>>(ylz, roff, csr, h0, N);
    // layer 1
    dense_gemm<256, false><<<dim3(gG, 2), 256, 0, stream>>>(h0, nullptr, WT1, b1, ylz, N);
    agg_relu<<<gA, 256, 0, stream>>>(ylz, roff, csr, h1, N);
    // layer 2 (64-wide): out = mean_gather(yl2) + z2
    dense_gemm<128, false><<<dim3(gG, 1), 256, 0, stream>>>(h1, nullptr, WT2, b2, ylz, N);
    agg_out64<<<gA, 256, 0, stream>>>(ylz, roff, csr, (float*)d_out, N);
}

// Round 9
// 316.105 us; speedup vs baseline: 1.1985x; 1.1985x over previous
//
#include <hip/hip_runtime.h>
#include <hip/hip_bf16.h>
#include <stdint.h>

#define D 128
#define BSH 9                 // bucket = 512 nodes
#define BKN 512               // nodes per bucket
#define TILE 8192             // edges per bin_edges block

typedef __attribute__((ext_vector_type(8))) short short8;
typedef __attribute__((ext_vector_type(4))) float f32x4;

__device__ inline float bf16lo(uint32_t u){ return __uint_as_float(u << 16); }
__device__ inline float bf16hi(uint32_t u){ return __uint_as_float(u & 0xffff0000u); }
__device__ inline unsigned short f2bf(float f){
    union { __hip_bfloat16 h; unsigned short u; } cvt;
    cvt.h = __float2bfloat16(f);
    return cvt.u;
}

#define ACC8(q) \
    acc[0] += bf16lo(q.x); acc[1] += bf16hi(q.x); \
    acc[2] += bf16lo(q.y); acc[3] += bf16hi(q.y); \
    acc[4] += bf16lo(q.z); acc[5] += bf16hi(q.z); \
    acc[6] += bf16lo(q.w); acc[7] += bf16hi(q.w);

#define ACC4(q) \
    acc[0] += bf16lo(q.x); acc[1] += bf16hi(q.x); \
    acc[2] += bf16lo(q.y); acc[3] += bf16hi(q.y);

// ---------- binned CSR build (bucket = dst >> 9) ----------
__global__ void count_bkt(const int* __restrict__ dst, int* __restrict__ cnt, int E, int nbk){
    __shared__ int h[256];
    int t = threadIdx.x;
    for (int i = t; i < nbk; i += 256) h[i] = 0;
    __syncthreads();
    for (int e = blockIdx.x * 256 + t; e < E; e += gridDim.x * 256)
        atomicAdd(&h[dst[e] >> BSH], 1);
    __syncthreads();
    for (int i = t; i < nbk; i += 256) if (h[i]) atomicAdd(&cnt[i], h[i]);
}

__global__ void scan_bkt(const int* __restrict__ cnt, int* __restrict__ base,
                         int* __restrict__ bfill, int nb, int E){
    __shared__ int s[256];
    __shared__ int carry;
    int t = threadIdx.x;
    if (t == 0) carry = 0;
    __syncthreads();
    for (int start = 0; start < nb; start += 256){
        int i = start + t;
        int v = (i < nb) ? cnt[i] : 0;
        s[t] = v;
        __syncthreads();
        for (int o = 1; o < 256; o <<= 1){
            int x = (t >= o) ? s[t - o] : 0;
            __syncthreads();
            s[t] += x;
            __syncthreads();
        }
        int excl = carry + s[t] - v;
        if (i < nb){ base[i] = excl; bfill[i] = excl; }
        __syncthreads();
        if (t == 255) carry += s[255];
        __syncthreads();
    }
    if (t == 0) base[nb] = E;
}

// LDS-staged scatter: tile -> hist -> scan -> reserve -> LDS reorder -> dense run writes
__global__ __launch_bounds__(256) void bin_edges(
    const int* __restrict__ src, const int* __restrict__ dst,
    int* __restrict__ bfill, uint32_t* __restrict__ binbuf, int E, int nbk)
{
    __shared__ int hist[256];
    __shared__ int hbase[257];
    __shared__ int gbase[256];
    __shared__ int cur[256];
    __shared__ int sc[256];
    __shared__ uint32_t stg[TILE];
    int t = threadIdx.x;
    int tile0 = blockIdx.x * TILE;
    int cnt = min(TILE, E - tile0);

    for (int i = t; i < nbk; i += 256) hist[i] = 0;
    __syncthreads();
    for (int i = t; i < cnt; i += 256)
        atomicAdd(&hist[dst[tile0 + i] >> BSH], 1);
    __syncthreads();
    int v = (t < nbk) ? hist[t] : 0;
    sc[t] = v;
    __syncthreads();
    for (int o = 1; o < 256; o <<= 1){
        int x = (t >= o) ? sc[t - o] : 0;
        __syncthreads();
        sc[t] += x;
        __syncthreads();
    }
    if (t < nbk){
        int ex = sc[t] - v;
        hbase[t] = ex; cur[t] = ex;
        gbase[t] = v ? atomicAdd(&bfill[t], v) : 0;
    }
    if (t == 0) hbase[nbk] = cnt;
    __syncthreads();
    for (int i = t; i < cnt; i += 256){
        int d = dst[tile0 + i];
        int s_ = src[tile0 + i];
        int b = d >> BSH;
        int p = atomicAdd(&cur[b], 1);
        stg[p] = (uint32_t)s_ | ((uint32_t)(d & (BKN - 1)) << 17);
    }
    __syncthreads();
    for (int i = t; i < cnt; i += 256){
        int lo = 0, hi = nbk;
        while (hi - lo > 1){
            int mid = (lo + hi) >> 1;
            if (hbase[mid] <= i) lo = mid; else hi = mid;
        }
        binbuf[(size_t)gbase[lo] + (i - hbase[lo])] = stg[i];
    }
}

// one block per 512-node bucket: histogram -> scan -> roff + local csr scatter
__global__ __launch_bounds__(256) void fill_bucket(
    const uint32_t* __restrict__ binbuf, const int* __restrict__ bktbase,
    int* __restrict__ roff, int* __restrict__ csr, int n, int nbk)
{
    __shared__ int hist[BKN];
    __shared__ int hist2[BKN];
    __shared__ int hb2[BKN];
    __shared__ int sc[256];
    int b = blockIdx.x, t = threadIdx.x;
    int e0 = bktbase[b], e1 = bktbase[b + 1];
    int v0 = b << BSH;
    int nv = min(BKN, n - v0);

    hist[t] = 0; hist[t + 256] = 0;
    hist2[t] = 0; hist2[t + 256] = 0;
    __syncthreads();
    for (int e = e0 + t; e < e1; e += 256)
        atomicAdd(&hist[binbuf[e] >> 17], 1);
    __syncthreads();
    int a0 = hist[2 * t], a1 = hist[2 * t + 1];
    int own = a0 + a1;
    sc[t] = own;
    __syncthreads();
    for (int o = 1; o < 256; o <<= 1){
        int x = (t >= o) ? sc[t - o] : 0;
        __syncthreads();
        sc[t] += x;
        __syncthreads();
    }
    int ex = sc[t] - own;
    hb2[2 * t] = ex;
    hb2[2 * t + 1] = ex + a0;
    __syncthreads();
    for (int i = t; i < nv; i += 256) roff[v0 + i] = e0 + hb2[i];
    if (b == nbk - 1 && t == 0) roff[n] = e1;
    for (int e = e0 + t; e < e1; e += 256){
        uint32_t p = binbuf[e];
        int local = p >> 17;
        int pos = e0 + hb2[local] + atomicAdd(&hist2[local], 1);
        csr[pos] = (int)(p & 0x1FFFFu);
    }
}

// ---------- weight pre-transpose: WT[j][k] = bf16(Wcat[k][j]), Wcat = [Wl | Wr], NC=2*DOUT cols ----------
__global__ void wt_prep(const float* __restrict__ Wl, const float* __restrict__ Wr,
                        unsigned short* __restrict__ WT, int dout){
    int nc = dout * 2;
    int idx = blockIdx.x * 256 + threadIdx.x;
    if (idx >= nc * 128) return;
    int k = idx & 127, j = idx >> 7;
    float w = (j < dout) ? Wl[k * dout + j] : Wr[k * dout + (j - dout)];
    WT[j * 128 + k] = f2bf(w);
}

// ---------- dense GEMM: ylz = X @ [Wl|Wr] + [0|b]  (M=n, N=NC, K=128) ----------
// grid = (M/128, NC/128). A-tile (128x128 bf16 = 32KB) staged in LDS with XOR swizzle
// (byte ^= (row&7)<<4) so fragment ds_read_b128 is 2-way (free) instead of 16-way.
// Swapped-operand MFMA: mfma(W-frag, X-frag) -> lane holds 4 consecutive out-cols -> uint2 store.
template<int NC, bool AF32>
__global__ __launch_bounds__(256, 2) void dense_gemm(
    const unsigned short* __restrict__ xb, const float* __restrict__ xf,
    const unsigned short* __restrict__ WT, const float* __restrict__ bias,
    unsigned short* __restrict__ ylz, int n)
{
    constexpr int DOUT = NC / 2;
    __shared__ __align__(16) char As[128 * 256];
    int tid = threadIdx.x, lane = tid & 63, wave = tid >> 6;
    int rbase = blockIdx.x * 128;
    int lrow = lane & 15, lk = (lane >> 4) * 8;
    int colbase = blockIdx.y * 128 + wave * 32;

    // W fragments from global (L2-hot; issued early, overlap with staging)
    short8 bfr[4][2];
    #pragma unroll
    for (int kk = 0; kk < 4; kk++)
        #pragma unroll
        for (int cf = 0; cf < 2; cf++)
            bfr[kk][cf] = *reinterpret_cast<const short8*>(
                WT + (size_t)(colbase + cf * 16 + lrow) * 128 + kk * 32 + lk);

    // ---- stage A tile into LDS, coalesced + swizzled ----
    {
        int cb = (tid & 15) * 16;             // byte col within 256B row
        #pragma unroll
        for (int i = 0; i < 8; i++){
            int row = i * 16 + (tid >> 4);
            int grow = min(rbase + row, n - 1);
            uint4 q;
            if (AF32){
                const float* p = xf + (size_t)grow * 128 + (cb >> 1);
                float4 f0 = *reinterpret_cast<const float4*>(p);
                float4 f1 = *reinterpret_cast<const float4*>(p + 4);
                q.x = (uint32_t)f2bf(f0.x) | ((uint32_t)f2bf(f0.y) << 16);
                q.y = (uint32_t)f2bf(f0.z) | ((uint32_t)f2bf(f0.w) << 16);
                q.z = (uint32_t)f2bf(f1.x) | ((uint32_t)f2bf(f1.y) << 16);
                q.w = (uint32_t)f2bf(f1.z) | ((uint32_t)f2bf(f1.w) << 16);
            } else {
                q = *reinterpret_cast<const uint4*>(xb + (size_t)grow * 128 + (cb >> 1));
            }
            *reinterpret_cast<uint4*>(As + row * 256 + (cb ^ ((row & 7) << 4))) = q;
        }
    }
    __syncthreads();

    f32x4 acc[8][2];
    #pragma unroll
    for (int fr = 0; fr < 8; fr++)
        #pragma unroll
        for (int cf = 0; cf < 2; cf++)
            acc[fr][cf] = (f32x4){0.f, 0.f, 0.f, 0.f};

    #pragma unroll
    for (int kk = 0; kk < 4; kk++){
        int cb = kk * 64 + (lane >> 4) * 16;
        #pragma unroll
        for (int fr = 0; fr < 8; fr++){
            int row = fr * 16 + lrow;
            short8 a = *reinterpret_cast<const short8*>(As + row * 256 + (cb ^ ((row & 7) << 4)));
            #pragma unroll
            for (int cf = 0; cf < 2; cf++)
                acc[fr][cf] = __builtin_amdgcn_mfma_f32_16x16x32_bf16(bfr[kk][cf], a, acc[fr][cf], 0, 0, 0);
        }
    }

    // bias per cf (col group), 4 consecutive cols per lane
    float4 bv[2];
    #pragma unroll
    for (int cf = 0; cf < 2; cf++){
        int cg = colbase + cf * 16 + (lane >> 4) * 4;
        bv[cf] = (cg >= DOUT) ? *reinterpret_cast<const float4*>(bias + (cg - DOUT))
                              : (float4){0.f, 0.f, 0.f, 0.f};
    }

    #pragma unroll
    for (int fr = 0; fr < 8; fr++){
        int row = rbase + fr * 16 + lrow;
        if (row < n){
            #pragma unroll
            for (int cf = 0; cf < 2; cf++){
                int cg = colbase + cf * 16 + (lane >> 4) * 4;
                uint2 o;
                o.x = (uint32_t)f2bf(acc[fr][cf][0] + bv[cf].x) |
                      ((uint32_t)f2bf(acc[fr][cf][1] + bv[cf].y) << 16);
                o.y = (uint32_t)f2bf(acc[fr][cf][2] + bv[cf].z) |
                      ((uint32_t)f2bf(acc[fr][cf][3] + bv[cf].w) << 16);
                *reinterpret_cast<uint2*>(ylz + (size_t)row * NC + cg) = o;
            }
        }
    }
}

// ---------- aggregation: h = relu(mean_gather(yl) + z), yl/z in ylz[N][256] ----------
__global__ __launch_bounds__(256, 4) void agg_relu(
    const unsigned short* __restrict__ ylz, const int* __restrict__ roff,
    const int* __restrict__ csr, unsigned short* __restrict__ hout, int n)
{
    int grp = threadIdx.x >> 4, li = threadIdx.x & 15;
    int v = blockIdx.x * 16 + grp;
    if (v >= n) return;
    int s0 = roff[v], s1 = roff[v + 1];
    const unsigned short* base = ylz + li * 8;
    float acc[8] = {0.f,0.f,0.f,0.f,0.f,0.f,0.f,0.f};
    int e = s0;
    for (; e + 8 <= s1; e += 8){
        int i0=csr[e],i1=csr[e+1],i2=csr[e+2],i3=csr[e+3];
        int i4=csr[e+4],i5=csr[e+5],i6=csr[e+6],i7=csr[e+7];
        uint4 q0 = *reinterpret_cast<const uint4*>(base + (size_t)i0 * 256);
        uint4 q1 = *reinterpret_cast<const uint4*>(base + (size_t)i1 * 256);
        uint4 q2 = *reinterpret_cast<const uint4*>(base + (size_t)i2 * 256);
        uint4 q3 = *reinterpret_cast<const uint4*>(base + (size_t)i3 * 256);
        uint4 q4 = *reinterpret_cast<const uint4*>(base + (size_t)i4 * 256);
        uint4 q5 = *reinterpret_cast<const uint4*>(base + (size_t)i5 * 256);
        uint4 q6 = *reinterpret_cast<const uint4*>(base + (size_t)i6 * 256);
        uint4 q7 = *reinterpret_cast<const uint4*>(base + (size_t)i7 * 256);
        ACC8(q0) ACC8(q1) ACC8(q2) ACC8(q3) ACC8(q4) ACC8(q5) ACC8(q6) ACC8(q7)
    }
    if (e < s1){
        int last = s1 - 1;
        int i0=csr[e];
        int i1=csr[min(e+1,last)],i2=csr[min(e+2,last)],i3=csr[min(e+3,last)];
        int i4=csr[min(e+4,last)],i5=csr[min(e+5,last)],i6=csr[min(e+6,last)],i7=csr[min(e+7,last)];
        uint4 z4 = make_uint4(0,0,0,0);
        uint4 q0 = *reinterpret_cast<const uint4*>(base + (size_t)i0 * 256);
        uint4 q1 = *reinterpret_cast<const uint4*>(base + (size_t)i1 * 256);
        uint4 q2 = *reinterpret_cast<const uint4*>(base + (size_t)i2 * 256);
        uint4 q3 = *reinterpret_cast<const uint4*>(base + (size_t)i3 * 256);
        uint4 q4 = *reinterpret_cast<const uint4*>(base + (size_t)i4 * 256);
        uint4 q5 = *reinterpret_cast<const uint4*>(base + (size_t)i5 * 256);
        uint4 q6 = *reinterpret_cast<const uint4*>(base + (size_t)i6 * 256);
        uint4 q7 = *reinterpret_cast<const uint4*>(base + (size_t)i7 * 256);
        if (e+1 > last) q1 = z4;
        if (e+2 > last) q2 = z4;
        if (e+3 > last) q3 = z4;
        if (e+4 > last) q4 = z4;
        if (e+5 > last) q5 = z4;
        if (e+6 > last) q6 = z4;
        if (e+7 > last) q7 = z4;
        ACC8(q0) ACC8(q1) ACC8(q2) ACC8(q3) ACC8(q4) ACC8(q5) ACC8(q6) ACC8(q7)
    }
    int d = s1 - s0;
    float inv = (d > 0) ? 1.0f / (float)d : 0.0f;
    uint4 zq = *reinterpret_cast<const uint4*>(ylz + (size_t)v * 256 + 128 + li * 8);
    float z0=bf16lo(zq.x), z1=bf16hi(zq.x), z2=bf16lo(zq.y), z3=bf16hi(zq.y);
    float z4_=bf16lo(zq.z), z5=bf16hi(zq.z), z6=bf16lo(zq.w), z7=bf16hi(zq.w);
    uint4 o;
    o.x = (uint32_t)f2bf(fmaxf(acc[0]*inv+z0,0.f)) | ((uint32_t)f2bf(fmaxf(acc[1]*inv+z1,0.f)) << 16);
    o.y = (uint32_t)f2bf(fmaxf(acc[2]*inv+z2,0.f)) | ((uint32_t)f2bf(fmaxf(acc[3]*inv+z3,0.f)) << 16);
    o.z = (uint32_t)f2bf(fmaxf(acc[4]*inv+z4_,0.f)) | ((uint32_t)f2bf(fmaxf(acc[5]*inv+z5,0.f)) << 16);
    o.w = (uint32_t)f2bf(fmaxf(acc[6]*inv+z6,0.f)) | ((uint32_t)f2bf(fmaxf(acc[7]*inv+z7,0.f)) << 16);
    *reinterpret_cast<uint4*>(hout + (size_t)v * 128 + li * 8) = o;
}

// ---------- final layer aggregation: out = mean_gather(yl2) + z2, fp32 out, ylz[N][128] ----------
__global__ __launch_bounds__(256, 4) void agg_out64(
    const unsigned short* __restrict__ ylz, const int* __restrict__ roff,
    const int* __restrict__ csr, float* __restrict__ out, int n)
{
    int grp = threadIdx.x >> 4, li = threadIdx.x & 15;
    int v = blockIdx.x * 16 + grp;
    if (v >= n) return;
    int s0 = roff[v], s1 = roff[v + 1];
    const unsigned short* base = ylz + li * 4;
    float acc[4] = {0.f,0.f,0.f,0.f};
    int e = s0;
    for (; e + 8 <= s1; e += 8){
        int i0=csr[e],i1=csr[e+1],i2=csr[e+2],i3=csr[e+3];
        int i4=csr[e+4],i5=csr[e+5],i6=csr[e+6],i7=csr[e+7];
        uint2 q0 = *reinterpret_cast<const uint2*>(base + (size_t)i0 * 128);
        uint2 q1 = *reinterpret_cast<const uint2*>(base + (size_t)i1 * 128);
        uint2 q2 = *reinterpret_cast<const uint2*>(base + (size_t)i2 * 128);
        uint2 q3 = *reinterpret_cast<const uint2*>(base + (size_t)i3 * 128);
        uint2 q4 = *reinterpret_cast<const uint2*>(base + (size_t)i4 * 128);
        uint2 q5 = *reinterpret_cast<const uint2*>(base + (size_t)i5 * 128);
        uint2 q6 = *reinterpret_cast<const uint2*>(base + (size_t)i6 * 128);
        uint2 q7 = *reinterpret_cast<const uint2*>(base + (size_t)i7 * 128);
        ACC4(q0) ACC4(q1) ACC4(q2) ACC4(q3) ACC4(q4) ACC4(q5) ACC4(q6) ACC4(q7)
    }
    if (e < s1){
        int last = s1 - 1;
        int i0=csr[e];
        int i1=csr[min(e+1,last)],i2=csr[min(e+2,last)],i3=csr[min(e+3,last)];
        int i4=csr[min(e+4,last)],i5=csr[min(e+5,last)],i6=csr[min(e+6,last)],i7=csr[min(e+7,last)];
        uint2 z2_ = make_uint2(0,0);
        uint2 q0 = *reinterpret_cast<const uint2*>(base + (size_t)i0 * 128);
        uint2 q1 = *reinterpret_cast<const uint2*>(base + (size_t)i1 * 128);
        uint2 q2 = *reinterpret_cast<const uint2*>(base + (size_t)i2 * 128);
        uint2 q3 = *reinterpret_cast<const uint2*>(base + (size_t)i3 * 128);
        uint2 q4 = *reinterpret_cast<const uint2*>(base + (size_t)i4 * 128);
        uint2 q5 = *reinterpret_cast<const uint2*>(base + (size_t)i5 * 128);
        uint2 q6 = *reinterpret_cast<const uint2*>(base + (size_t)i6 * 128);
        uint2 q7 = *reinterpret_cast<const uint2*>(base + (size_t)i7 * 128);
        if (e+1 > last) q1 = z2_;
        if (e+2 > last) q2 = z2_;
        if (e+3 > last) q3 = z2_;
        if (e+4 > last) q4 = z2_;
        if (e+5 > last) q5 = z2_;
        if (e+6 > last) q6 = z2_;
        if (e+7 > last) q7 = z2_;
        ACC4(q0) ACC4(q1) ACC4(q2) ACC4(q3) ACC4(q4) ACC4(q5) ACC4(q6) ACC4(q7)
    }
    int d = s1 - s0;
    float inv = (d > 0) ? 1.0f / (float)d : 0.0f;
    uint2 zq = *reinterpret_cast<const uint2*>(ylz + (size_t)v * 128 + 64 + li * 4);
    float4 o;
    o.x = acc[0]*inv + bf16lo(zq.x);
    o.y = acc[1]*inv + bf16hi(zq.x);
    o.z = acc[2]*inv + bf16lo(zq.y);
    o.w = acc[3]*inv + bf16hi(zq.y);
    *reinterpret_cast<float4*>(out + (size_t)v * 64 + li * 4) = o;
}

extern "C" void kernel_launch(void* const* d_in, const int* in_sizes, int n_in,
                              void* d_out, int out_size, void* d_ws, size_t ws_size,
                              hipStream_t stream)
{
    const float* x   = (const float*)d_in[0];
    const int*   ei  = (const int*)d_in[1];
    const float* Wl0 = (const float*)d_in[2];
    const float* Wr0 = (const float*)d_in[3];
    const float* b0  = (const float*)d_in[4];
    const float* Wl1 = (const float*)d_in[5];
    const float* Wr1 = (const float*)d_in[6];
    const float* b1  = (const float*)d_in[7];
    const float* Wl2 = (const float*)d_in[8];
    const float* Wr2 = (const float*)d_in[9];
    const float* b2  = (const float*)d_in[10];

    int N = in_sizes[0] / D;
    int E = in_sizes[1] / 2;
    const int* src = ei;
    const int* dst = ei + E;
    int NBK = (N + BKN - 1) >> BSH;

    char* ws = (char*)d_ws;
    size_t off = 0;
    auto alloc = [&](size_t bytes) -> void* {
        void* p = ws + off;
        off = (off + bytes + 255) & ~(size_t)255;
        return p;
    };
    int*      bktcnt  = (int*)alloc((size_t)NBK * 4);
    int*      bktbase = (int*)alloc(((size_t)NBK + 1) * 4);
    int*      bktfill = (int*)alloc((size_t)NBK * 4);
    int*      roff    = (int*)alloc(((size_t)N + 1) * 4);
    int*      csr     = (int*)alloc((size_t)E * 4);
    unsigned short* ylz = (unsigned short*)alloc((size_t)N * 256 * 2);   // also overlays binbuf
    unsigned short* h0  = (unsigned short*)alloc((size_t)N * D * 2);
    unsigned short* h1  = (unsigned short*)alloc((size_t)N * D * 2);
    unsigned short* WT0 = (unsigned short*)alloc((size_t)256 * 128 * 2);
    unsigned short* WT1 = (unsigned short*)alloc((size_t)256 * 128 * 2);
    unsigned short* WT2 = (unsigned short*)alloc((size_t)128 * 128 * 2);
    uint32_t* binbuf = (uint32_t*)ylz;   // binbuf dead before first ylz write

    hipMemsetAsync(bktcnt, 0, (size_t)NBK * 4, stream);

    count_bkt<<<512, 256, 0, stream>>>(dst, bktcnt, E, NBK);
    scan_bkt<<<1, 256, 0, stream>>>(bktcnt, bktbase, bktfill, NBK, E);
    bin_edges<<<(E + TILE - 1) / TILE, 256, 0, stream>>>(src, dst, bktfill, binbuf, E, NBK);
    fill_bucket<<<NBK, 256, 0, stream>>>(binbuf, bktbase, roff, csr, N, NBK);

    wt_prep<<<(256 * 128 + 255) / 256, 256, 0, stream>>>(Wl0, Wr0, WT0, 128);
    wt_prep<<<(256 * 128 + 255) / 256, 256, 0, stream>>>(Wl1, Wr1, WT1, 128);
    wt_prep<<<(128 * 128 + 255) / 256, 256, 0, stream>>>(Wl2, Wr2, WT2, 64);

    int gG = (N + 127) / 128;
    int gA = (N + 15) / 16;

    // layer 0: ylz = x @ [Wl0|Wr0] + [0|b0]  (fp32 A, converted during staging)
    dense_gemm<256, true ><<<dim3(gG, 2), 256, 0, stream>>>(nullptr, x, WT0, b0, ylz, N);
    agg_relu<<<gA, 256, 0, stream>>>(ylz, roff, csr, h0, N);
    // layer 1
    dense_gemm<256, false><<<dim3(gG, 2), 256, 0, stream>>>(h0, nullptr, WT1, b1, ylz, N);
    agg_relu<<<gA, 256, 0, stream>>>(ylz, roff, csr, h1, N);
    // layer 2 (64-wide): out = mean_gather(yl2) + z2
    dense_gemm<128, false><<<dim3(gG, 1), 256, 0, stream>>>(h1, nullptr, WT2, b2, ylz, N);
    agg_out64<<<gA, 256, 0, stream>>>(ylz, roff, csr, (float*)d_out, N);
}

// Round 10
// 283.594 us; speedup vs baseline: 1.3359x; 1.1146x over previous
//
#include <hip/hip_runtime.h>
#include <hip/hip_bf16.h>
#include <stdint.h>

#define D 128
#define BSH 9                 // bucket = 512 nodes
#define BKN 512               // nodes per bucket
#define TILE 4096             // edges per bin_edges block
#define CAPB 10240            // per-bucket slot capacity (expected ~8163, 20-sigma headroom)

typedef __attribute__((ext_vector_type(8))) short short8;
typedef __attribute__((ext_vector_type(4))) float f32x4;

typedef __attribute__((address_space(1))) const void gvoid;
typedef __attribute__((address_space(3))) void lvoid;

__device__ inline float bf16lo(uint32_t u){ return __uint_as_float(u << 16); }
__device__ inline float bf16hi(uint32_t u){ return __uint_as_float(u & 0xffff0000u); }
__device__ inline unsigned short f2bf(float f){
    union { __hip_bfloat16 h; unsigned short u; } cvt;
    cvt.h = __float2bfloat16(f);
    return cvt.u;
}

#define ACC8(q) \
    acc[0] += bf16lo(q.x); acc[1] += bf16hi(q.x); \
    acc[2] += bf16lo(q.y); acc[3] += bf16hi(q.y); \
    acc[4] += bf16lo(q.z); acc[5] += bf16hi(q.z); \
    acc[6] += bf16lo(q.w); acc[7] += bf16hi(q.w);

#define ACC4(q) \
    acc[0] += bf16lo(q.x); acc[1] += bf16hi(q.x); \
    acc[2] += bf16lo(q.y); acc[3] += bf16hi(q.y);

// ---------- binned edge scatter: direct 2-pass, padded per-bucket regions ----------
__global__ __launch_bounds__(256) void bin_edges(
    const int* __restrict__ src, const int* __restrict__ dst,
    int* __restrict__ bfill, uint32_t* __restrict__ binbuf, int E, int nbk)
{
    __shared__ int hist[256];
    __shared__ int cur[256];
    int t = threadIdx.x;
    int tile0 = blockIdx.x * TILE;
    int cnt = min(TILE, E - tile0);

    for (int i = t; i < nbk; i += 256) hist[i] = 0;
    __syncthreads();
    for (int i = t; i < cnt; i += 256)
        atomicAdd(&hist[dst[tile0 + i] >> BSH], 1);
    __syncthreads();
    for (int i = t; i < nbk; i += 256){
        int h = hist[i];
        int base = h ? atomicAdd(&bfill[i], h) : 0;
        cur[i] = i * CAPB + base;
    }
    __syncthreads();
    for (int i = t; i < cnt; i += 256){
        int d = dst[tile0 + i];
        int b = d >> BSH;
        int p = atomicAdd(&cur[b], 1);
        binbuf[p] = (uint32_t)src[tile0 + i] | ((uint32_t)(d & (BKN - 1)) << 17);
    }
}

// one block per 512-node bucket: histogram -> scan -> roff/rend + local csr scatter
__global__ __launch_bounds__(256) void fill_bucket(
    const uint32_t* __restrict__ binbuf, const int* __restrict__ bcnt,
    int* __restrict__ roff, int* __restrict__ rend, int* __restrict__ csr, int n, int nbk)
{
    __shared__ int hist[BKN];
    __shared__ int hist2[BKN];
    __shared__ int hb2[BKN];
    __shared__ int sc[256];
    int b = blockIdx.x, t = threadIdx.x;
    int e0 = b * CAPB;
    int e1 = e0 + bcnt[b];
    int v0 = b << BSH;
    int nv = min(BKN, n - v0);

    hist[t] = 0; hist[t + 256] = 0;
    hist2[t] = 0; hist2[t + 256] = 0;
    __syncthreads();
    for (int e = e0 + t; e < e1; e += 256)
        atomicAdd(&hist[binbuf[e] >> 17], 1);
    __syncthreads();
    int a0 = hist[2 * t], a1 = hist[2 * t + 1];
    int own = a0 + a1;
    sc[t] = own;
    __syncthreads();
    for (int o = 1; o < 256; o <<= 1){
        int x = (t >= o) ? sc[t - o] : 0;
        __syncthreads();
        sc[t] += x;
        __syncthreads();
    }
    int ex = sc[t] - own;
    hb2[2 * t] = ex;
    hb2[2 * t + 1] = ex + a0;
    __syncthreads();
    for (int i = t; i < nv; i += 256){
        roff[v0 + i] = e0 + hb2[i];
        rend[v0 + i] = e0 + hb2[i] + hist[i];
    }
    for (int e = e0 + t; e < e1; e += 256){
        uint32_t p = binbuf[e];
        int local = p >> 17;
        int pos = e0 + hb2[local] + atomicAdd(&hist2[local], 1);
        csr[pos] = (int)(p & 0x1FFFFu);
    }
}

// ---------- weight pre-transpose: WT[j][k] = bf16(Wcat[k][j]), Wcat = [Wl | Wr], NC=2*DOUT cols ----------
__global__ void wt_prep(const float* __restrict__ Wl, const float* __restrict__ Wr,
                        unsigned short* __restrict__ WT, int dout){
    int nc = dout * 2;
    int idx = blockIdx.x * 256 + threadIdx.x;
    if (idx >= nc * 128) return;
    int k = idx & 127, j = idx >> 7;
    float w = (j < dout) ? Wl[k * dout + j] : Wr[k * dout + (j - dout)];
    WT[j * 128 + k] = f2bf(w);
}

// ---------- dense GEMM: ylz = X @ [Wl|Wr] + [0|b]  (M=n, N=NC, K=128) ----------
// grid = (M/128, NC/128). A-tile (128x128 bf16 = 32KB) staged into LDS:
//   bf16 path: global_load_lds dwordx4, linear LDS dest + pre-XOR'd per-lane source
//   fp32 path (layer 0): reg staging with convert + swizzled LDS write
// XOR swizzle byte ^= (row&7)<<4 keeps fragment ds_read_b128 conflict-free.
// Swapped-operand MFMA: mfma(W-frag, X-frag) -> lane holds 4 consecutive out-cols -> uint2 store.
template<int NC, bool AF32>
__global__ __launch_bounds__(256, 3) void dense_gemm(
    const unsigned short* __restrict__ xb, const float* __restrict__ xf,
    const unsigned short* __restrict__ WT, const float* __restrict__ bias,
    unsigned short* __restrict__ ylz, int n)
{
    constexpr int DOUT = NC / 2;
    __shared__ __align__(16) char As[128 * 256];
    int tid = threadIdx.x, lane = tid & 63, wave = tid >> 6;
    int rbase = blockIdx.x * 128;
    int lrow = lane & 15, lk = (lane >> 4) * 8;
    int colbase = blockIdx.y * 128 + wave * 32;

    // W fragments from global (L2-hot; issued early, overlap with staging)
    short8 bfr[4][2];
    #pragma unroll
    for (int kk = 0; kk < 4; kk++)
        #pragma unroll
        for (int cf = 0; cf < 2; cf++)
            bfr[kk][cf] = *reinterpret_cast<const short8*>(
                WT + (size_t)(colbase + cf * 16 + lrow) * 128 + kk * 32 + lk);

    // ---- stage A tile into LDS ----
    if constexpr (AF32){
        int cb = (tid & 15) * 16;             // byte col within 256B row
        #pragma unroll
        for (int i = 0; i < 8; i++){
            int row = i * 16 + (tid >> 4);
            int grow = min(rbase + row, n - 1);
            const float* p = xf + (size_t)grow * 128 + (cb >> 1);
            float4 f0 = *reinterpret_cast<const float4*>(p);
            float4 f1 = *reinterpret_cast<const float4*>(p + 4);
            uint4 q;
            q.x = (uint32_t)f2bf(f0.x) | ((uint32_t)f2bf(f0.y) << 16);
            q.y = (uint32_t)f2bf(f0.z) | ((uint32_t)f2bf(f0.w) << 16);
            q.z = (uint32_t)f2bf(f1.x) | ((uint32_t)f2bf(f1.y) << 16);
            q.w = (uint32_t)f2bf(f1.z) | ((uint32_t)f2bf(f1.w) << 16);
            *reinterpret_cast<uint4*>(As + row * 256 + (cb ^ ((row & 7) << 4))) = q;
        }
    } else {
        int cb = (lane & 15) * 16;
        #pragma unroll
        for (int i = 0; i < 8; i++){
            int row = i * 16 + (tid >> 4);            // lane-linear within wave
            int grow = min(rbase + row, n - 1);
            const unsigned short* gsrc = xb + (size_t)grow * 128 + ((cb ^ ((row & 7) << 4)) >> 1);
            __builtin_amdgcn_global_load_lds(
                (gvoid*)gsrc,
                (lvoid*)(As + (i * 16 + wave * 4) * 256),
                16, 0, 0);
        }
    }
    __syncthreads();

    f32x4 acc[8][2];
    #pragma unroll
    for (int fr = 0; fr < 8; fr++)
        #pragma unroll
        for (int cf = 0; cf < 2; cf++)
            acc[fr][cf] = (f32x4){0.f, 0.f, 0.f, 0.f};

    #pragma unroll
    for (int kk = 0; kk < 4; kk++){
        int cb = kk * 64 + (lane >> 4) * 16;
        #pragma unroll
        for (int fr = 0; fr < 8; fr++){
            int row = fr * 16 + lrow;
            short8 a = *reinterpret_cast<const short8*>(As + row * 256 + (cb ^ ((row & 7) << 4)));
            #pragma unroll
            for (int cf = 0; cf < 2; cf++)
                acc[fr][cf] = __builtin_amdgcn_mfma_f32_16x16x32_bf16(bfr[kk][cf], a, acc[fr][cf], 0, 0, 0);
        }
    }

    // bias per cf (col group), 4 consecutive cols per lane
    float4 bv[2];
    #pragma unroll
    for (int cf = 0; cf < 2; cf++){
        int cg = colbase + cf * 16 + (lane >> 4) * 4;
        bv[cf] = (cg >= DOUT) ? *reinterpret_cast<const float4*>(bias + (cg - DOUT))
                              : (float4){0.f, 0.f, 0.f, 0.f};
    }

    #pragma unroll
    for (int fr = 0; fr < 8; fr++){
        int row = rbase + fr * 16 + lrow;
        if (row < n){
            #pragma unroll
            for (int cf = 0; cf < 2; cf++){
                int cg = colbase + cf * 16 + (lane >> 4) * 4;
                uint2 o;
                o.x = (uint32_t)f2bf(acc[fr][cf][0] + bv[cf].x) |
                      ((uint32_t)f2bf(acc[fr][cf][1] + bv[cf].y) << 16);
                o.y = (uint32_t)f2bf(acc[fr][cf][2] + bv[cf].z) |
                      ((uint32_t)f2bf(acc[fr][cf][3] + bv[cf].w) << 16);
                *reinterpret_cast<uint2*>(ylz + (size_t)row * NC + cg) = o;
            }
        }
    }
}

// ---------- aggregation: h = relu(mean_gather(yl) + z), yl/z in ylz[N][256] ----------
__global__ __launch_bounds__(256, 4) void agg_relu(
    const unsigned short* __restrict__ ylz, const int* __restrict__ roff,
    const int* __restrict__ rend,
    const int* __restrict__ csr, unsigned short* __restrict__ hout, int n)
{
    int grp = threadIdx.x >> 4, li = threadIdx.x & 15;
    int v = blockIdx.x * 16 + grp;
    if (v >= n) return;
    int s0 = roff[v], s1 = rend[v];
    const unsigned short* base = ylz + li * 8;
    float acc[8] = {0.f,0.f,0.f,0.f,0.f,0.f,0.f,0.f};
    int e = s0;
    for (; e + 8 <= s1; e += 8){
        int i0=csr[e],i1=csr[e+1],i2=csr[e+2],i3=csr[e+3];
        int i4=csr[e+4],i5=csr[e+5],i6=csr[e+6],i7=csr[e+7];
        uint4 q0 = *reinterpret_cast<const uint4*>(base + (size_t)i0 * 256);
        uint4 q1 = *reinterpret_cast<const uint4*>(base + (size_t)i1 * 256);
        uint4 q2 = *reinterpret_cast<const uint4*>(base + (size_t)i2 * 256);
        uint4 q3 = *reinterpret_cast<const uint4*>(base + (size_t)i3 * 256);
        uint4 q4 = *reinterpret_cast<const uint4*>(base + (size_t)i4 * 256);
        uint4 q5 = *reinterpret_cast<const uint4*>(base + (size_t)i5 * 256);
        uint4 q6 = *reinterpret_cast<const uint4*>(base + (size_t)i6 * 256);
        uint4 q7 = *reinterpret_cast<const uint4*>(base + (size_t)i7 * 256);
        ACC8(q0) ACC8(q1) ACC8(q2) ACC8(q3) ACC8(q4) ACC8(q5) ACC8(q6) ACC8(q7)
    }
    if (e < s1){
        int last = s1 - 1;
        int i0=csr[e];
        int i1=csr[min(e+1,last)],i2=csr[min(e+2,last)],i3=csr[min(e+3,last)];
        int i4=csr[min(e+4,last)],i5=csr[min(e+5,last)],i6=csr[min(e+6,last)],i7=csr[min(e+7,last)];
        uint4 z4 = make_uint4(0,0,0,0);
        uint4 q0 = *reinterpret_cast<const uint4*>(base + (size_t)i0 * 256);
        uint4 q1 = *reinterpret_cast<const uint4*>(base + (size_t)i1 * 256);
        uint4 q2 = *reinterpret_cast<const uint4*>(base + (size_t)i2 * 256);
        uint4 q3 = *reinterpret_cast<const uint4*>(base + (size_t)i3 * 256);
        uint4 q4 = *reinterpret_cast<const uint4*>(base + (size_t)i4 * 256);
        uint4 q5 = *reinterpret_cast<const uint4*>(base + (size_t)i5 * 256);
        uint4 q6 = *reinterpret_cast<const uint4*>(base + (size_t)i6 * 256);
        uint4 q7 = *reinterpret_cast<const uint4*>(base + (size_t)i7 * 256);
        if (e+1 > last) q1 = z4;
        if (e+2 > last) q2 = z4;
        if (e+3 > last) q3 = z4;
        if (e+4 > last) q4 = z4;
        if (e+5 > last) q5 = z4;
        if (e+6 > last) q6 = z4;
        if (e+7 > last) q7 = z4;
        ACC8(q0) ACC8(q1) ACC8(q2) ACC8(q3) ACC8(q4) ACC8(q5) ACC8(q6) ACC8(q7)
    }
    int d = s1 - s0;
    float inv = (d > 0) ? 1.0f / (float)d : 0.0f;
    uint4 zq = *reinterpret_cast<const uint4*>(ylz + (size_t)v * 256 + 128 + li * 8);
    float z0=bf16lo(zq.x), z1=bf16hi(zq.x), z2=bf16lo(zq.y), z3=bf16hi(zq.y);
    float z4_=bf16lo(zq.z), z5=bf16hi(zq.z), z6=bf16lo(zq.w), z7=bf16hi(zq.w);
    uint4 o;
    o.x = (uint32_t)f2bf(fmaxf(acc[0]*inv+z0,0.f)) | ((uint32_t)f2bf(fmaxf(acc[1]*inv+z1,0.f)) << 16);
    o.y = (uint32_t)f2bf(fmaxf(acc[2]*inv+z2,0.f)) | ((uint32_t)f2bf(fmaxf(acc[3]*inv+z3,0.f)) << 16);
    o.z = (uint32_t)f2bf(fmaxf(acc[4]*inv+z4_,0.f)) | ((uint32_t)f2bf(fmaxf(acc[5]*inv+z5,0.f)) << 16);
    o.w = (uint32_t)f2bf(fmaxf(acc[6]*inv+z6,0.f)) | ((uint32_t)f2bf(fmaxf(acc[7]*inv+z7,0.f)) << 16);
    *reinterpret_cast<uint4*>(hout + (size_t)v * 128 + li * 8) = o;
}

// ---------- final layer aggregation: out = mean_gather(yl2) + z2, fp32 out, ylz[N][128] ----------
__global__ __launch_bounds__(256, 4) void agg_out64(
    const unsigned short* __restrict__ ylz, const int* __restrict__ roff,
    const int* __restrict__ rend,
    const int* __restrict__ csr, float* __restrict__ out, int n)
{
    int grp = threadIdx.x >> 4, li = threadIdx.x & 15;
    int v = blockIdx.x * 16 + grp;
    if (v >= n) return;
    int s0 = roff[v], s1 = rend[v];
    const unsigned short* base = ylz + li * 4;
    float acc[4] = {0.f,0.f,0.f,0.f};
    int e = s0;
    for (; e + 8 <= s1; e += 8){
        int i0=csr[e],i1=csr[e+1],i2=csr[e+2],i3=csr[e+3];
        int i4=csr[e+4],i5=csr[e+5],i6=csr[e+6],i7=csr[e+7];
        uint2 q0 = *reinterpret_cast<const uint2*>(base + (size_t)i0 * 128);
        uint2 q1 = *reinterpret_cast<const uint2*>(base + (size_t)i1 * 128);
        uint2 q2 = *reinterpret_cast<const uint2*>(base + (size_t)i2 * 128);
        uint2 q3 = *reinterpret_cast<const uint2*>(base + (size_t)i3 * 128);
        uint2 q4 = *reinterpret_cast<const uint2*>(base + (size_t)i4 * 128);
        uint2 q5 = *reinterpret_cast<const uint2*>(base + (size_t)i5 * 128);
        uint2 q6 = *reinterpret_cast<const uint2*>(base + (size_t)i6 * 128);
        uint2 q7 = *reinterpret_cast<const uint2*>(base + (size_t)i7 * 128);
        ACC4(q0) ACC4(q1) ACC4(q2) ACC4(q3) ACC4(q4) ACC4(q5) ACC4(q6) ACC4(q7)
    }
    if (e < s1){
        int last = s1 - 1;
        int i0=csr[e];
        int i1=csr[min(e+1,last)],i2=csr[min(e+2,last)],i3=csr[min(e+3,last)];
        int i4=csr[min(e+4,last)],i5=csr[min(e+5,last)],i6=csr[min(e+6,last)],i7=csr[min(e+7,last)];
        uint2 z2_ = make_uint2(0,0);
        uint2 q0 = *reinterpret_cast<const uint2*>(base + (size_t)i0 * 128);
        uint2 q1 = *reinterpret_cast<const uint2*>(base + (size_t)i1 * 128);
        uint2 q2 = *reinterpret_cast<const uint2*>(base + (size_t)i2 * 128);
        uint2 q3 = *reinterpret_cast<const uint2*>(base + (size_t)i3 * 128);
        uint2 q4 = *reinterpret_cast<const uint2*>(base + (size_t)i4 * 128);
        uint2 q5 = *reinterpret_cast<const uint2*>(base + (size_t)i5 * 128);
        uint2 q6 = *reinterpret_cast<const uint2*>(base + (size_t)i6 * 128);
        uint2 q7 = *reinterpret_cast<const uint2*>(base + (size_t)i7 * 128);
        if (e+1 > last) q1 = z2_;
        if (e+2 > last) q2 = z2_;
        if (e+3 > last) q3 = z2_;
        if (e+4 > last) q4 = z2_;
        if (e+5 > last) q5 = z2_;
        if (e+6 > last) q6 = z2_;
        if (e+7 > last) q7 = z2_;
        ACC4(q0) ACC4(q1) ACC4(q2) ACC4(q3) ACC4(q4) ACC4(q5) ACC4(q6) ACC4(q7)
    }
    int d = s1 - s0;
    float inv = (d > 0) ? 1.0f / (float)d : 0.0f;
    uint2 zq = *reinterpret_cast<const uint2*>(ylz + (size_t)v * 128 + 64 + li * 4);
    float4 o;
    o.x = acc[0]*inv + bf16lo(zq.x);
    o.y = acc[1]*inv + bf16hi(zq.x);
    o.z = acc[2]*inv + bf16lo(zq.y);
    o.w = acc[3]*inv + bf16hi(zq.y);
    *reinterpret_cast<float4*>(out + (size_t)v * 64 + li * 4) = o;
}

extern "C" void kernel_launch(void* const* d_in, const int* in_sizes, int n_in,
                              void* d_out, int out_size, void* d_ws, size_t ws_size,
                              hipStream_t stream)
{
    const float* x   = (const float*)d_in[0];
    const int*   ei  = (const int*)d_in[1];
    const float* Wl0 = (const float*)d_in[2];
    const float* Wr0 = (const float*)d_in[3];
    const float* b0  = (const float*)d_in[4];
    const float* Wl1 = (const float*)d_in[5];
    const float* Wr1 = (const float*)d_in[6];
    const float* b1  = (const float*)d_in[7];
    const float* Wl2 = (const float*)d_in[8];
    const float* Wr2 = (const float*)d_in[9];
    const float* b2  = (const float*)d_in[10];

    int N = in_sizes[0] / D;
    int E = in_sizes[1] / 2;
    const int* src = ei;
    const int* dst = ei + E;
    int NBK = (N + BKN - 1) >> BSH;      // 196

    char* ws = (char*)d_ws;
    size_t off = 0;
    auto alloc = [&](size_t bytes) -> void* {
        void* p = ws + off;
        off = (off + bytes + 255) & ~(size_t)255;
        return p;
    };
    int*      bfill  = (int*)alloc((size_t)NBK * 4);
    int*      roff   = (int*)alloc((size_t)N * 4);
    int*      rend   = (int*)alloc((size_t)N * 4);
    int*      csr    = (int*)alloc((size_t)NBK * CAPB * 4);
    unsigned short* ylz = (unsigned short*)alloc((size_t)N * 256 * 2);   // also overlays binbuf
    unsigned short* h0  = (unsigned short*)alloc((size_t)N * D * 2);
    unsigned short* h1  = (unsigned short*)alloc((size_t)N * D * 2);
    unsigned short* WT0 = (unsigned short*)alloc((size_t)256 * 128 * 2);
    unsigned short* WT1 = (unsigned short*)alloc((size_t)256 * 128 * 2);
    unsigned short* WT2 = (unsigned short*)alloc((size_t)128 * 128 * 2);
    uint32_t* binbuf = (uint32_t*)ylz;   // binbuf (8 MB) dead before first ylz write

    hipMemsetAsync(bfill, 0, (size_t)NBK * 4, stream);

    bin_edges<<<(E + TILE - 1) / TILE, 256, 0, stream>>>(src, dst, bfill, binbuf, E, NBK);
    fill_bucket<<<NBK, 256, 0, stream>>>(binbuf, bfill, roff, rend, csr, N, NBK);

    wt_prep<<<(256 * 128 + 255) / 256, 256, 0, stream>>>(Wl0, Wr0, WT0, 128);
    wt_prep<<<(256 * 128 + 255) / 256, 256, 0, stream>>>(Wl1, Wr1, WT1, 128);
    wt_prep<<<(128 * 128 + 255) / 256, 256, 0, stream>>>(Wl2, Wr2, WT2, 64);

    int gG = (N + 127) / 128;
    int gA = (N + 15) / 16;

    // layer 0: ylz = x @ [Wl0|Wr0] + [0|b0]  (fp32 A, converted during staging)
    dense_gemm<256, true ><<<dim3(gG, 2), 256, 0, stream>>>(nullptr, x, WT0, b0, ylz, N);
    agg_relu<<<gA, 256, 0, stream>>>(ylz, roff, rend, csr, h0, N);
    // layer 1
    dense_gemm<256, false><<<dim3(gG, 2), 256, 0, stream>>>(h0, nullptr, WT1, b1, ylz, N);
    agg_relu<<<gA, 256, 0, stream>>>(ylz, roff, rend, csr, h1, N);
    // layer 2 (64-wide): out = mean_gather(yl2) + z2
    dense_gemm<128, false><<<dim3(gG, 1), 256, 0, stream>>>(h1, nullptr, WT2, b2, ylz, N);
    agg_out64<<<gA, 256, 0, stream>>>(ylz, roff, rend, csr, (float*)d_out, N);
}

// Round 11
// 281.572 us; speedup vs baseline: 1.3455x; 1.0072x over previous
//
#include <hip/hip_runtime.h>
#include <hip/hip_bf16.h>
#include <stdint.h>

#define D 128
#define BSH 8                 // bucket = 256 nodes
#define BKN 256               // nodes per bucket
#define TILE 4096             // edges per bin_edges block
#define CAPB 5376             // per-bucket slot capacity (mean ~4096, sd ~64, 20-sigma headroom)

typedef __attribute__((ext_vector_type(8))) short short8;
typedef __attribute__((ext_vector_type(4))) float f32x4;

typedef __attribute__((address_space(1))) const void gvoid;
typedef __attribute__((address_space(3))) void lvoid;

__device__ inline float bf16lo(uint32_t u){ return __uint_as_float(u << 16); }
__device__ inline float bf16hi(uint32_t u){ return __uint_as_float(u & 0xffff0000u); }
__device__ inline unsigned short f2bf(float f){
    union { __hip_bfloat16 h; unsigned short u; } cvt;
    cvt.h = __float2bfloat16(f);
    return cvt.u;
}

#define ACC8(q) \
    acc[0] += bf16lo(q.x); acc[1] += bf16hi(q.x); \
    acc[2] += bf16lo(q.y); acc[3] += bf16hi(q.y); \
    acc[4] += bf16lo(q.z); acc[5] += bf16hi(q.z); \
    acc[6] += bf16lo(q.w); acc[7] += bf16hi(q.w);

#define ACC4(q) \
    acc[0] += bf16lo(q.x); acc[1] += bf16hi(q.x); \
    acc[2] += bf16lo(q.y); acc[3] += bf16hi(q.y);

// ---------- binned edge scatter: direct 2-pass, padded per-bucket regions ----------
__global__ __launch_bounds__(256) void bin_edges(
    const int* __restrict__ src, const int* __restrict__ dst,
    int* __restrict__ bfill, uint32_t* __restrict__ binbuf, int E, int nbk)
{
    __shared__ int hist[400];
    __shared__ int cur[400];
    int t = threadIdx.x;
    int tile0 = blockIdx.x * TILE;
    int cnt = min(TILE, E - tile0);

    for (int i = t; i < nbk; i += 256) hist[i] = 0;
    __syncthreads();
    for (int i = t; i < cnt; i += 256)
        atomicAdd(&hist[dst[tile0 + i] >> BSH], 1);
    __syncthreads();
    for (int i = t; i < nbk; i += 256){
        int h = hist[i];
        int base = h ? atomicAdd(&bfill[i], h) : 0;
        cur[i] = i * CAPB + base;
    }
    __syncthreads();
    for (int i = t; i < cnt; i += 256){
        int d = dst[tile0 + i];
        int b = d >> BSH;
        int p = atomicAdd(&cur[b], 1);
        binbuf[p] = (uint32_t)src[tile0 + i] | ((uint32_t)(d & (BKN - 1)) << 17);
    }
}

// one block per 256-node bucket: histogram -> scan -> roff/rend + local csr scatter
__global__ __launch_bounds__(256) void fill_bucket(
    const uint32_t* __restrict__ binbuf, const int* __restrict__ bcnt,
    int* __restrict__ roff, int* __restrict__ rend, int* __restrict__ csr, int n, int nbk)
{
    __shared__ int hist[BKN];
    __shared__ int hist2[BKN];
    __shared__ int hb[BKN];
    __shared__ int sc[256];
    int b = blockIdx.x, t = threadIdx.x;
    int e0 = b * CAPB;
    int e1 = e0 + bcnt[b];
    int v0 = b << BSH;
    int nv = min(BKN, n - v0);

    hist[t] = 0; hist2[t] = 0;
    __syncthreads();
    for (int e = e0 + t; e < e1; e += 256)
        atomicAdd(&hist[binbuf[e] >> 17], 1);
    __syncthreads();
    int own = hist[t];
    sc[t] = own;
    __syncthreads();
    for (int o = 1; o < 256; o <<= 1){
        int x = (t >= o) ? sc[t - o] : 0;
        __syncthreads();
        sc[t] += x;
        __syncthreads();
    }
    int ex = sc[t] - own;
    hb[t] = ex;
    if (t < nv){
        roff[v0 + t] = e0 + ex;
        rend[v0 + t] = e0 + ex + own;
    }
    __syncthreads();
    for (int e = e0 + t; e < e1; e += 256){
        uint32_t p = binbuf[e];
        int local = p >> 17;
        int pos = e0 + hb[local] + atomicAdd(&hist2[local], 1);
        csr[pos] = (int)(p & 0x1FFFFu);
    }
}

// ---------- weight pre-transpose: WT[j][k] = bf16(Wcat[k][j]), Wcat = [Wl | Wr], NC=2*DOUT cols ----------
__global__ void wt_prep(const float* __restrict__ Wl, const float* __restrict__ Wr,
                        unsigned short* __restrict__ WT, int dout){
    int nc = dout * 2;
    int idx = blockIdx.x * 256 + threadIdx.x;
    if (idx >= nc * 128) return;
    int k = idx & 127, j = idx >> 7;
    float w = (j < dout) ? Wl[k * dout + j] : Wr[k * dout + (j - dout)];
    WT[j * 128 + k] = f2bf(w);
}

// ---------- dense GEMM: ylz = X @ [Wl|Wr] + [0|b]  (M=n, N=NC, K=128) ----------
// grid = (M/128, NC/128). A-tile (128x128 bf16 = 32KB) staged into LDS:
//   bf16 path: global_load_lds dwordx4, linear LDS dest + pre-XOR'd per-lane source
//   fp32 path (layer 0): reg staging with convert + swizzled LDS write
// XOR swizzle byte ^= (row&7)<<4 keeps fragment ds_read_b128 conflict-free.
// Swapped-operand MFMA: mfma(W-frag, X-frag) -> lane holds 4 consecutive out-cols -> uint2 store.
template<int NC, bool AF32>
__global__ __launch_bounds__(256, 3) void dense_gemm(
    const unsigned short* __restrict__ xb, const float* __restrict__ xf,
    const unsigned short* __restrict__ WT, const float* __restrict__ bias,
    unsigned short* __restrict__ ylz, int n)
{
    constexpr int DOUT = NC / 2;
    __shared__ __align__(16) char As[128 * 256];
    int tid = threadIdx.x, lane = tid & 63, wave = tid >> 6;
    int rbase = blockIdx.x * 128;
    int lrow = lane & 15, lk = (lane >> 4) * 8;
    int colbase = blockIdx.y * 128 + wave * 32;

    // W fragments from global (L2-hot; issued early, overlap with staging)
    short8 bfr[4][2];
    #pragma unroll
    for (int kk = 0; kk < 4; kk++)
        #pragma unroll
        for (int cf = 0; cf < 2; cf++)
            bfr[kk][cf] = *reinterpret_cast<const short8*>(
                WT + (size_t)(colbase + cf * 16 + lrow) * 128 + kk * 32 + lk);

    // ---- stage A tile into LDS ----
    if constexpr (AF32){
        int cb = (tid & 15) * 16;             // byte col within 256B row
        #pragma unroll
        for (int i = 0; i < 8; i++){
            int row = i * 16 + (tid >> 4);
            int grow = min(rbase + row, n - 1);
            const float* p = xf + (size_t)grow * 128 + (cb >> 1);
            float4 f0 = *reinterpret_cast<const float4*>(p);
            float4 f1 = *reinterpret_cast<const float4*>(p + 4);
            uint4 q;
            q.x = (uint32_t)f2bf(f0.x) | ((uint32_t)f2bf(f0.y) << 16);
            q.y = (uint32_t)f2bf(f0.z) | ((uint32_t)f2bf(f0.w) << 16);
            q.z = (uint32_t)f2bf(f1.x) | ((uint32_t)f2bf(f1.y) << 16);
            q.w = (uint32_t)f2bf(f1.z) | ((uint32_t)f2bf(f1.w) << 16);
            *reinterpret_cast<uint4*>(As + row * 256 + (cb ^ ((row & 7) << 4))) = q;
        }
    } else {
        int cb = (lane & 15) * 16;
        #pragma unroll
        for (int i = 0; i < 8; i++){
            int row = i * 16 + (tid >> 4);            // lane-linear within wave
            int grow = min(rbase + row, n - 1);
            const unsigned short* gsrc = xb + (size_t)grow * 128 + ((cb ^ ((row & 7) << 4)) >> 1);
            __builtin_amdgcn_global_load_lds(
                (gvoid*)gsrc,
                (lvoid*)(As + (i * 16 + wave * 4) * 256),
                16, 0, 0);
        }
    }
    __syncthreads();

    f32x4 acc[8][2];
    #pragma unroll
    for (int fr = 0; fr < 8; fr++)
        #pragma unroll
        for (int cf = 0; cf < 2; cf++)
            acc[fr][cf] = (f32x4){0.f, 0.f, 0.f, 0.f};

    #pragma unroll
    for (int kk = 0; kk < 4; kk++){
        int cb = kk * 64 + (lane >> 4) * 16;
        #pragma unroll
        for (int fr = 0; fr < 8; fr++){
            int row = fr * 16 + lrow;
            short8 a = *reinterpret_cast<const short8*>(As + row * 256 + (cb ^ ((row & 7) << 4)));
            #pragma unroll
            for (int cf = 0; cf < 2; cf++)
                acc[fr][cf] = __builtin_amdgcn_mfma_f32_16x16x32_bf16(bfr[kk][cf], a, acc[fr][cf], 0, 0, 0);
        }
    }

    // bias per cf (col group), 4 consecutive cols per lane
    float4 bv[2];
    #pragma unroll
    for (int cf = 0; cf < 2; cf++){
        int cg = colbase + cf * 16 + (lane >> 4) * 4;
        bv[cf] = (cg >= DOUT) ? *reinterpret_cast<const float4*>(bias + (cg - DOUT))
                              : (float4){0.f, 0.f, 0.f, 0.f};
    }

    #pragma unroll
    for (int fr = 0; fr < 8; fr++){
        int row = rbase + fr * 16 + lrow;
        if (row < n){
            #pragma unroll
            for (int cf = 0; cf < 2; cf++){
                int cg = colbase + cf * 16 + (lane >> 4) * 4;
                uint2 o;
                o.x = (uint32_t)f2bf(acc[fr][cf][0] + bv[cf].x) |
                      ((uint32_t)f2bf(acc[fr][cf][1] + bv[cf].y) << 16);
                o.y = (uint32_t)f2bf(acc[fr][cf][2] + bv[cf].z) |
                      ((uint32_t)f2bf(acc[fr][cf][3] + bv[cf].w) << 16);
                *reinterpret_cast<uint2*>(ylz + (size_t)row * NC + cg) = o;
            }
        }
    }
}

// ---------- aggregation: h = relu(mean_gather(yl) + z), yl/z in ylz[N][256] ----------
__global__ __launch_bounds__(256, 6) void agg_relu(
    const unsigned short* __restrict__ ylz, const int* __restrict__ roff,
    const int* __restrict__ rend,
    const int* __restrict__ csr, unsigned short* __restrict__ hout, int n)
{
    int grp = threadIdx.x >> 4, li = threadIdx.x & 15;
    int v = blockIdx.x * 16 + grp;
    if (v >= n) return;
    int s0 = roff[v], s1 = rend[v];
    const unsigned short* base = ylz + li * 8;
    float acc[8] = {0.f,0.f,0.f,0.f,0.f,0.f,0.f,0.f};
    int e = s0;
    for (; e + 8 <= s1; e += 8){
        int i0=csr[e],i1=csr[e+1],i2=csr[e+2],i3=csr[e+3];
        int i4=csr[e+4],i5=csr[e+5],i6=csr[e+6],i7=csr[e+7];
        uint4 q0 = *reinterpret_cast<const uint4*>(base + (size_t)i0 * 256);
        uint4 q1 = *reinterpret_cast<const uint4*>(base + (size_t)i1 * 256);
        uint4 q2 = *reinterpret_cast<const uint4*>(base + (size_t)i2 * 256);
        uint4 q3 = *reinterpret_cast<const uint4*>(base + (size_t)i3 * 256);
        uint4 q4 = *reinterpret_cast<const uint4*>(base + (size_t)i4 * 256);
        uint4 q5 = *reinterpret_cast<const uint4*>(base + (size_t)i5 * 256);
        uint4 q6 = *reinterpret_cast<const uint4*>(base + (size_t)i6 * 256);
        uint4 q7 = *reinterpret_cast<const uint4*>(base + (size_t)i7 * 256);
        ACC8(q0) ACC8(q1) ACC8(q2) ACC8(q3) ACC8(q4) ACC8(q5) ACC8(q6) ACC8(q7)
    }
    if (e < s1){
        int last = s1 - 1;
        int i0=csr[e];
        int i1=csr[min(e+1,last)],i2=csr[min(e+2,last)],i3=csr[min(e+3,last)];
        int i4=csr[min(e+4,last)],i5=csr[min(e+5,last)],i6=csr[min(e+6,last)],i7=csr[min(e+7,last)];
        uint4 z4 = make_uint4(0,0,0,0);
        uint4 q0 = *reinterpret_cast<const uint4*>(base + (size_t)i0 * 256);
        uint4 q1 = *reinterpret_cast<const uint4*>(base + (size_t)i1 * 256);
        uint4 q2 = *reinterpret_cast<const uint4*>(base + (size_t)i2 * 256);
        uint4 q3 = *reinterpret_cast<const uint4*>(base + (size_t)i3 * 256);
        uint4 q4 = *reinterpret_cast<const uint4*>(base + (size_t)i4 * 256);
        uint4 q5 = *reinterpret_cast<const uint4*>(base + (size_t)i5 * 256);
        uint4 q6 = *reinterpret_cast<const uint4*>(base + (size_t)i6 * 256);
        uint4 q7 = *reinterpret_cast<const uint4*>(base + (size_t)i7 * 256);
        if (e+1 > last) q1 = z4;
        if (e+2 > last) q2 = z4;
        if (e+3 > last) q3 = z4;
        if (e+4 > last) q4 = z4;
        if (e+5 > last) q5 = z4;
        if (e+6 > last) q6 = z4;
        if (e+7 > last) q7 = z4;
        ACC8(q0) ACC8(q1) ACC8(q2) ACC8(q3) ACC8(q4) ACC8(q5) ACC8(q6) ACC8(q7)
    }
    int d = s1 - s0;
    float inv = (d > 0) ? 1.0f / (float)d : 0.0f;
    uint4 zq = *reinterpret_cast<const uint4*>(ylz + (size_t)v * 256 + 128 + li * 8);
    float z0=bf16lo(zq.x), z1=bf16hi(zq.x), z2=bf16lo(zq.y), z3=bf16hi(zq.y);
    float z4_=bf16lo(zq.z), z5=bf16hi(zq.z), z6=bf16lo(zq.w), z7=bf16hi(zq.w);
    uint4 o;
    o.x = (uint32_t)f2bf(fmaxf(acc[0]*inv+z0,0.f)) | ((uint32_t)f2bf(fmaxf(acc[1]*inv+z1,0.f)) << 16);
    o.y = (uint32_t)f2bf(fmaxf(acc[2]*inv+z2,0.f)) | ((uint32_t)f2bf(fmaxf(acc[3]*inv+z3,0.f)) << 16);
    o.z = (uint32_t)f2bf(fmaxf(acc[4]*inv+z4_,0.f)) | ((uint32_t)f2bf(fmaxf(acc[5]*inv+z5,0.f)) << 16);
    o.w = (uint32_t)f2bf(fmaxf(acc[6]*inv+z6,0.f)) | ((uint32_t)f2bf(fmaxf(acc[7]*inv+z7,0.f)) << 16);
    *reinterpret_cast<uint4*>(hout + (size_t)v * 128 + li * 8) = o;
}

// ---------- final layer aggregation: out = mean_gather(yl2) + z2, fp32 out, ylz[N][128] ----------
__global__ __launch_bounds__(256, 6) void agg_out64(
    const unsigned short* __restrict__ ylz, const int* __restrict__ roff,
    const int* __restrict__ rend,
    const int* __restrict__ csr, float* __restrict__ out, int n)
{
    int grp = threadIdx.x >> 4, li = threadIdx.x & 15;
    int v = blockIdx.x * 16 + grp;
    if (v >= n) return;
    int s0 = roff[v], s1 = rend[v];
    const unsigned short* base = ylz + li * 4;
    float acc[4] = {0.f,0.f,0.f,0.f};
    int e = s0;
    for (; e + 8 <= s1; e += 8){
        int i0=csr[e],i1=csr[e+1],i2=csr[e+2],i3=csr[e+3];
        int i4=csr[e+4],i5=csr[e+5],i6=csr[e+6],i7=csr[e+7];
        uint2 q0 = *reinterpret_cast<const uint2*>(base + (size_t)i0 * 128);
        uint2 q1 = *reinterpret_cast<const uint2*>(base + (size_t)i1 * 128);
        uint2 q2 = *reinterpret_cast<const uint2*>(base + (size_t)i2 * 128);
        uint2 q3 = *reinterpret_cast<const uint2*>(base + (size_t)i3 * 128);
        uint2 q4 = *reinterpret_cast<const uint2*>(base + (size_t)i4 * 128);
        uint2 q5 = *reinterpret_cast<const uint2*>(base + (size_t)i5 * 128);
        uint2 q6 = *reinterpret_cast<const uint2*>(base + (size_t)i6 * 128);
        uint2 q7 = *reinterpret_cast<const uint2*>(base + (size_t)i7 * 128);
        ACC4(q0) ACC4(q1) ACC4(q2) ACC4(q3) ACC4(q4) ACC4(q5) ACC4(q6) ACC4(q7)
    }
    if (e < s1){
        int last = s1 - 1;
        int i0=csr[e];
        int i1=csr[min(e+1,last)],i2=csr[min(e+2,last)],i3=csr[min(e+3,last)];
        int i4=csr[min(e+4,last)],i5=csr[min(e+5,last)],i6=csr[min(e+6,last)],i7=csr[min(e+7,last)];
        uint2 z2_ = make_uint2(0,0);
        uint2 q0 = *reinterpret_cast<const uint2*>(base + (size_t)i0 * 128);
        uint2 q1 = *reinterpret_cast<const uint2*>(base + (size_t)i1 * 128);
        uint2 q2 = *reinterpret_cast<const uint2*>(base + (size_t)i2 * 128);
        uint2 q3 = *reinterpret_cast<const uint2*>(base + (size_t)i3 * 128);
        uint2 q4 = *reinterpret_cast<const uint2*>(base + (size_t)i4 * 128);
        uint2 q5 = *reinterpret_cast<const uint2*>(base + (size_t)i5 * 128);
        uint2 q6 = *reinterpret_cast<const uint2*>(base + (size_t)i6 * 128);
        uint2 q7 = *reinterpret_cast<const uint2*>(base + (size_t)i7 * 128);
        if (e+1 > last) q1 = z2_;
        if (e+2 > last) q2 = z2_;
        if (e+3 > last) q3 = z2_;
        if (e+4 > last) q4 = z2_;
        if (e+5 > last) q5 = z2_;
        if (e+6 > last) q6 = z2_;
        if (e+7 > last) q7 = z2_;
        ACC4(q0) ACC4(q1) ACC4(q2) ACC4(q3) ACC4(q4) ACC4(q5) ACC4(q6) ACC4(q7)
    }
    int d = s1 - s0;
    float inv = (d > 0) ? 1.0f / (float)d : 0.0f;
    uint2 zq = *reinterpret_cast<const uint2*>(ylz + (size_t)v * 128 + 64 + li * 4);
    float4 o;
    o.x = acc[0]*inv + bf16lo(zq.x);
    o.y = acc[1]*inv + bf16hi(zq.x);
    o.z = acc[2]*inv + bf16lo(zq.y);
    o.w = acc[3]*inv + bf16hi(zq.y);
    *reinterpret_cast<float4*>(out + (size_t)v * 64 + li * 4) = o;
}

extern "C" void kernel_launch(void* const* d_in, const int* in_sizes, int n_in,
                              void* d_out, int out_size, void* d_ws, size_t ws_size,
                              hipStream_t stream)
{
    const float* x   = (const float*)d_in[0];
    const int*   ei  = (const int*)d_in[1];
    const float* Wl0 = (const float*)d_in[2];
    const float* Wr0 = (const float*)d_in[3];
    const float* b0  = (const float*)d_in[4];
    const float* Wl1 = (const float*)d_in[5];
    const float* Wr1 = (const float*)d_in[6];
    const float* b1  = (const float*)d_in[7];
    const float* Wl2 = (const float*)d_in[8];
    const float* Wr2 = (const float*)d_in[9];
    const float* b2  = (const float*)d_in[10];

    int N = in_sizes[0] / D;
    int E = in_sizes[1] / 2;
    const int* src = ei;
    const int* dst = ei + E;
    int NBK = (N + BKN - 1) >> BSH;      // 391 for N=100000

    char* ws = (char*)d_ws;
    size_t off = 0;
    auto alloc = [&](size_t bytes) -> void* {
        void* p = ws + off;
        off = (off + bytes + 255) & ~(size_t)255;
        return p;
    };
    int*      bfill  = (int*)alloc((size_t)NBK * 4);
    int*      roff   = (int*)alloc((size_t)N * 4);
    int*      rend   = (int*)alloc((size_t)N * 4);
    int*      csr    = (int*)alloc((size_t)NBK * CAPB * 4);
    unsigned short* ylz = (unsigned short*)alloc((size_t)N * 256 * 2);   // also overlays binbuf
    unsigned short* h0  = (unsigned short*)alloc((size_t)N * D * 2);
    unsigned short* h1  = (unsigned short*)alloc((size_t)N * D * 2);
    unsigned short* WT0 = (unsigned short*)alloc((size_t)256 * 128 * 2);
    unsigned short* WT1 = (unsigned short*)alloc((size_t)256 * 128 * 2);
    unsigned short* WT2 = (unsigned short*)alloc((size_t)128 * 128 * 2);
    uint32_t* binbuf = (uint32_t*)ylz;   // binbuf (8.4 MB) dead before first ylz write

    hipMemsetAsync(bfill, 0, (size_t)NBK * 4, stream);

    bin_edges<<<(E + TILE - 1) / TILE, 256, 0, stream>>>(src, dst, bfill, binbuf, E, NBK);
    fill_bucket<<<NBK, 256, 0, stream>>>(binbuf, bfill, roff, rend, csr, N, NBK);

    wt_prep<<<(256 * 128 + 255) / 256, 256, 0, stream>>>(Wl0, Wr0, WT0, 128);
    wt_prep<<<(256 * 128 + 255) / 256, 256, 0, stream>>>(Wl1, Wr1, WT1, 128);
    wt_prep<<<(128 * 128 + 255) / 256, 256, 0, stream>>>(Wl2, Wr2, WT2, 64);

    int gG = (N + 127) / 128;
    int gA = (N + 15) / 16;

    // layer 0: ylz = x @ [Wl0|Wr0] + [0|b0]  (fp32 A, converted during staging)
    dense_gemm<256, true ><<<dim3(gG, 2), 256, 0, stream>>>(nullptr, x, WT0, b0, ylz, N);
    agg_relu<<<gA, 256, 0, stream>>>(ylz, roff, rend, csr, h0, N);
    // layer 1
    dense_gemm<256, false><<<dim3(gG, 2), 256, 0, stream>>>(h0, nullptr, WT1, b1, ylz, N);
    agg_relu<<<gA, 256, 0, stream>>>(ylz, roff, rend, csr, h1, N);
    // layer 2 (64-wide): out = mean_gather(yl2) + z2
    dense_gemm<128, false><<<dim3(gG, 1), 256, 0, stream>>>(h1, nullptr, WT2, b2, ylz, N);
    agg_out64<<<gA, 256, 0, stream>>>(ylz, roff, rend, csr, (float*)d_out, N);
}